// Round 17
// baseline (74.563 us; speedup 1.0000x reference)
//
#include <hip/hip_runtime.h>

#define DEV __device__ __forceinline__

typedef __bf16 bf16;
typedef __bf16 bf16x8 __attribute__((ext_vector_type(8)));
typedef __bf16 bf16x4 __attribute__((ext_vector_type(4)));
typedef float f32x4 __attribute__((ext_vector_type(4)));
typedef float f32x16 __attribute__((ext_vector_type(16)));
typedef unsigned int u32x4 __attribute__((ext_vector_type(4)));

// 1/sqrt(512) * log2(e): scores pre-scaled so softmax uses exp2 directly
#define SCALE_F (0.04419417382415922f * 1.4426950408889634f)

DEV void gload_lds16(const void* g, void* l) {
  __builtin_amdgcn_global_load_lds(
      (const __attribute__((address_space(1))) void*)g,
      (__attribute__((address_space(3))) void*)l, 16, 0, 0);
}

DEV f32x4 mfma16(bf16x8 a, bf16x8 b, f32x4 c) {
  return __builtin_amdgcn_mfma_f32_16x16x32_bf16(a, b, c, 0, 0, 0);
}
DEV f32x16 mfma32(bf16x8 a, bf16x8 b, f32x16 c) {
  return __builtin_amdgcn_mfma_f32_32x32x16_bf16(a, b, c, 0, 0, 0);
}

DEV unsigned int pkbf(float a, float b) {
  unsigned short ua = __builtin_bit_cast(unsigned short, (bf16)a);
  unsigned short ub = __builtin_bit_cast(unsigned short, (bf16)b);
  return (unsigned int)ua | ((unsigned int)ub << 16);
}

// ---------------------------------------------------------------------------
// prep v2 (R13): blocks 0..255 -> weight prep; 256..767 -> Q transpose.
// ---------------------------------------------------------------------------
__global__ __launch_bounds__(256) void prep(
    const float* __restrict__ Q,
    const float* __restrict__ Wq, const float* __restrict__ bq,
    const float* __restrict__ Wk, const float* __restrict__ bk,
    const float* __restrict__ Wv, const float* __restrict__ bv,
    const float* __restrict__ Wo,
    bf16* __restrict__ Wf, float* __restrict__ biasf, bf16* __restrict__ Wor,
    bf16* __restrict__ Qt) {
  __shared__ float tile[64][65];
  int bid = blockIdx.x;
  int t = threadIdx.x;
  if (bid < 256) {
    int r0 = bid * 8;
    for (int idx = t; idx < 1024; idx += 256) {  // 8 rows x 128 float4
      int rl = idx >> 7, c4 = idx & 127;
      int row = r0 + rl;
      if (row < 1536) {
        const float* src;
        float scale = 1.0f;
        if (row < 512)       { src = Wq + (size_t)row * 512; scale = SCALE_F; }
        else if (row < 1024) { src = Wk + (size_t)(row - 512) * 512; }
        else                 { src = Wv + (size_t)(row - 1024) * 512; }
        float4 v = ((const float4*)src)[c4];
        bf16x4 o;
        o[0] = (bf16)(v.x * scale);
        o[1] = (bf16)(v.y * scale);
        o[2] = (bf16)(v.z * scale);
        o[3] = (bf16)(v.w * scale);
        *(bf16x4*)(Wf + (size_t)row * 512 + c4 * 4) = o;
      } else {
        int r = row - 1536;
#pragma unroll
        for (int e = 0; e < 4; ++e) {
          int c2 = c4 * 4 + e;
          Wor[(size_t)r * 512 + c2] =
              (bf16)Wo[(size_t)r * 512 + (c2 & 63) * 8 + (c2 >> 6)];
        }
      }
    }
    if (t < 8 && r0 + t < 1536) {
      int row = r0 + t;
      float bb;
      if (row < 512)       bb = bq[row] * SCALE_F;
      else if (row < 1024) bb = bk[row - 512];
      else                 bb = bv[row - 1024];
      biasf[row] = bb;
    }
  } else {
    int id2 = bid - 256;
    int n0 = (id2 & 31) * 64;
    int d0 = ((id2 >> 5) & 7) * 64;
    int b = id2 >> 8;
    int r = t >> 2, cw = t & 3;
    const float* src = Q + ((size_t)(b * 512 + d0 + r)) * 2048 + n0 + cw * 16;
#pragma unroll
    for (int e4 = 0; e4 < 4; ++e4) {
      float4 v = *(const float4*)(src + e4 * 4);
      tile[r][cw * 16 + e4 * 4 + 0] = v.x;
      tile[r][cw * 16 + e4 * 4 + 1] = v.y;
      tile[r][cw * 16 + e4 * 4 + 2] = v.z;
      tile[r][cw * 16 + e4 * 4 + 3] = v.w;
    }
    __syncthreads();
    bf16x8 o0{}, o1{};
#pragma unroll
    for (int e = 0; e < 8; ++e) {
      o0[e] = (bf16)tile[cw * 16 + e][r];
      o1[e] = (bf16)tile[cw * 16 + 8 + e][r];
    }
    bf16* dst = Qt + ((size_t)(b * 2048 + n0 + r)) * 512 + d0 + cw * 16;
    *(bf16x8*)dst = o0;
    *((bf16x8*)dst + 1) = o1;
  }
}

// ---------------------------------------------------------------------------
// qkv_gemm v8: 128x64 tile, BK=32, 16 K-steps, 4-buffer depth-2 counted
// vmcnt pipeline (R15 template). LDS 48KB -> 3 blocks/CU. Per step: 3
// gload_lds (2 A + 1 B) -> vmcnt(6) -> barrier -> compute (8 mfma).
// 64B-row bank swizzle: chunk ^= (row>>1)&3 (banks = 16*(row&1) +
// 4*(g^((row>>1)&3)) -> 8 distinct over 8 rows -> 2-way only).
// XCD chunk swizzle on 1-D grid 768. Epilogue: qp / kp / vt (pre-tiled V).
// ---------------------------------------------------------------------------
__global__ __launch_bounds__(256) void qkv_gemm(
    const bf16* __restrict__ Wf, const bf16* __restrict__ Qt,
    const float* __restrict__ biasf,
    bf16* __restrict__ qp, bf16* __restrict__ kp, bf16* __restrict__ vt) {
  __shared__ bf16 Al[4][128 * 32];
  __shared__ bf16 Bl[4][64 * 32];
  int hbid = blockIdx.x;
  int o = (hbid & 7) * 96 + (hbid >> 3);
  int cx = o % 12;
  int py = (o / 12) & 31;
  int b = o / 384;
  int c0 = cx * 128;
  int p0 = py * 64;
  int tid = threadIdx.x, w = tid >> 6, lane = tid & 63;
  int wm = w >> 1, wn = w & 1;
  int g = lane >> 4, l15 = lane & 15;

  const bf16* Abase = Wf + (size_t)c0 * 512;
  const bf16* Bbase = Qt + ((size_t)b * 2048 + p0) * 512;

  // staging: thread t covers row t>>2 (64 rows/issue), 16B chunk t&3.
  int srow = tid >> 2;           // 0..63
  int sc = tid & 3;

  f32x4 acc[4][2] = {};

  // prologue: issue steps 0 and 1
#pragma unroll
  for (int t0 = 0; t0 < 2; ++t0) {
    int k0 = t0 * 32;
#pragma unroll
    for (int i = 0; i < 2; ++i) {
      int row = i * 64 + srow;
      int ch = sc ^ ((row >> 1) & 3);
      gload_lds16(Abase + (size_t)row * 512 + k0 + ch * 8,
                  Al[t0] + (i * 64 + w * 16) * 32);
    }
    {
      int ch = sc ^ ((srow >> 1) & 3);
      gload_lds16(Bbase + (size_t)srow * 512 + k0 + ch * 8,
                  Bl[t0] + w * 16 * 32);
    }
  }

  for (int ks = 0; ks < 16; ++ks) {
    int cur = ks & 3;
    int nb = (ks + 2) & 3;
    int kp2 = (ks + 2 < 16) ? ks + 2 : 15;  // clamped redundant issue
    int k0n = kp2 * 32;
#pragma unroll
    for (int i = 0; i < 2; ++i) {
      int row = i * 64 + srow;
      int ch = sc ^ ((row >> 1) & 3);
      gload_lds16(Abase + (size_t)row * 512 + k0n + ch * 8,
                  Al[nb] + (i * 64 + w * 16) * 32);
    }
    {
      int ch = sc ^ ((srow >> 1) & 3);
      gload_lds16(Bbase + (size_t)srow * 512 + k0n + ch * 8,
                  Bl[nb] + w * 16 * 32);
    }

    asm volatile("s_waitcnt vmcnt(6)" ::: "memory");
    __builtin_amdgcn_s_barrier();
    __builtin_amdgcn_sched_barrier(0);
    asm volatile("" ::: "memory");

    bf16x8 a[4], bb[2];
#pragma unroll
    for (int mi = 0; mi < 4; ++mi) {
      int row = wm * 64 + mi * 16 + l15;
      a[mi] = *(const bf16x8*)(Al[cur] + row * 32 +
                               ((g ^ ((row >> 1) & 3)) << 3));
    }
#pragma unroll
    for (int ni = 0; ni < 2; ++ni) {
      int row = wn * 32 + ni * 16 + l15;
      bb[ni] = *(const bf16x8*)(Bl[cur] + row * 32 +
                                ((g ^ ((row >> 1) & 3)) << 3));
    }
#pragma unroll
    for (int mi = 0; mi < 4; ++mi)
#pragma unroll
      for (int ni = 0; ni < 2; ++ni)
        acc[mi][ni] = mfma16(a[mi], bb[ni], acc[mi][ni]);
    asm volatile("" ::: "memory");
  }

#pragma unroll
  for (int mi = 0; mi < 4; ++mi) {
#pragma unroll
    for (int ni = 0; ni < 2; ++ni) {
#pragma unroll
      for (int r = 0; r < 4; ++r) {
        int row = c0 + wm * 64 + mi * 16 + g * 4 + r;
        int p = p0 + wn * 32 + ni * 16 + l15;
        float val = acc[mi][ni][r] + biasf[row];
        bf16 hv = (bf16)val;
        if (row < 512) {
          int c = row;
          qp[(((size_t)b * 8 + (c & 7)) * 2048 + p) * 64 + (c >> 3)] = hv;
        } else if (row < 1024) {
          int c = row - 512;
          kp[(((size_t)b * 8 + (c & 7)) * 2048 + p) * 64 + (c >> 3)] = hv;
        } else {
          int c = row - 1024;       // c = d*8 + h
          int d = c >> 3, hh = c & 7;
          vt[((((size_t)b * 8 + hh) * 32 + (p >> 6)) * 64 + d) * 64 +
             (p & 63)] = hv;
        }
      }
    }
  }
}

// ---------------------------------------------------------------------------
// attn_k v12 (unchanged from R16): counted-vmcnt depth-2 pipeline, pre-tiled
// V, in-register P (32x32 MFMA + permlane32_swap), XCD swizzle.
// ---------------------------------------------------------------------------
__global__ __launch_bounds__(512, 4) void attn_k(
    const bf16* __restrict__ qp, const bf16* __restrict__ kp,
    const bf16* __restrict__ vt, bf16* __restrict__ Op,
    float* __restrict__ mbuf, float* __restrict__ lbuf, int TS) {
  __shared__ bf16 Ks[4][64 * 64];
  __shared__ bf16 Vs[4][64 * 64];
  int hbid = blockIdx.x;
  int o = (hbid & 7) * 64 + (hbid >> 3);
  int q0 = (o & 7) * 256;
  int bh = (o >> 3) & 15;
  int z = o >> 7;
  int tid = threadIdx.x, w = tid >> 6, lane = tid & 63;
  int l31 = lane & 31, hi = lane >> 5;

  bf16x8 qreg[4];
#pragma unroll
  for (int kd = 0; kd < 4; ++kd)
    qreg[kd] = *(const bf16x8*)(
        qp + ((size_t)bh * 2048 + q0 + w * 32 + l31) * 64 + kd * 16 + hi * 8);

  int krow = tid >> 3;            // 0..63
  int kch = (tid & 7) ^ (krow & 7);

  const bf16* Kall = kp + (size_t)bh * 2048 * 64 + (size_t)z * TS * 4096;
  const bf16* Vall = vt + ((size_t)bh * 32 + (size_t)z * TS) * 4096;

  // prologue: issue steps 0 and 1 (TS >= 8 always)
  gload_lds16(Kall + (size_t)krow * 64 + kch * 8, Ks[0] + w * 512);
  gload_lds16(Vall + (size_t)krow * 64 + kch * 8, Vs[0] + w * 512);
  gload_lds16(Kall + 4096 + (size_t)krow * 64 + kch * 8, Ks[1] + w * 512);
  gload_lds16(Vall + 4096 + (size_t)krow * 64 + kch * 8, Vs[1] + w * 512);

  f32x16 oacc0 = {}, oacc1 = {};
  float mrow = -1e30f, rs = 0.0f;

  for (int t = 0; t < TS; ++t) {
    int cur = t & 3;
    int nb = (t + 2) & 3;
    int tp = (t + 2 < TS) ? t + 2 : TS - 1;  // clamped redundant issue

    gload_lds16(Kall + (size_t)tp * 4096 + (size_t)krow * 64 + kch * 8,
                Ks[nb] + w * 512);
    gload_lds16(Vall + (size_t)tp * 4096 + (size_t)krow * 64 + kch * 8,
                Vs[nb] + w * 512);

    // wait for step-t's pair (oldest 2 of 6 outstanding), then rendezvous
    asm volatile("s_waitcnt vmcnt(4)" ::: "memory");
    __builtin_amdgcn_s_barrier();
    __builtin_amdgcn_sched_barrier(0);
    asm volatile("" ::: "memory");

    f32x16 st0 = {}, st1 = {};
    __builtin_amdgcn_s_setprio(1);
#pragma unroll
    for (int kd = 0; kd < 4; ++kd) {
      int sw = ((kd * 2 + hi) ^ (l31 & 7)) << 3;
      bf16x8 kb0 = *(const bf16x8*)(Ks[cur] + l31 * 64 + sw);
      bf16x8 kb1 = *(const bf16x8*)(Ks[cur] + (32 + l31) * 64 + sw);
      st0 = mfma32(kb0, qreg[kd], st0);
      st1 = mfma32(kb1, qreg[kd], st1);
    }
    __builtin_amdgcn_s_setprio(0);

    float rm = st0[0];
#pragma unroll
    for (int r = 1; r < 16; ++r) rm = fmaxf(rm, st0[r]);
#pragma unroll
    for (int r = 0; r < 16; ++r) rm = fmaxf(rm, st1[r]);
    rm = fmaxf(rm, __shfl_xor(rm, 32));

    if (__any(rm > mrow + 8.0f)) {
      float nm = fmaxf(mrow, rm);
      float esc = __builtin_amdgcn_exp2f(mrow - nm);
      mrow = nm;
      rs *= esc;
#pragma unroll
      for (int r = 0; r < 16; ++r) {
        int ql = (r & 3) + 8 * (r >> 2) + 4 * hi;
        float er = __shfl(esc, ql, 64);
        oacc0[r] *= er;
        oacc1[r] *= er;
      }
    }

    bf16x8 pa[4];
#pragma unroll
    for (int tile = 0; tile < 2; ++tile) {
      float pv[16];
#pragma unroll
      for (int r = 0; r < 16; ++r) {
        float v = __builtin_amdgcn_exp2f((tile ? st1[r] : st0[r]) - mrow);
        pv[r] = v;
        rs += v;
      }
      unsigned int r0d0 = pkbf(pv[0], pv[1]),   r0d1 = pkbf(pv[2], pv[3]);
      unsigned int r1d0 = pkbf(pv[4], pv[5]),   r1d1 = pkbf(pv[6], pv[7]);
      unsigned int r2d0 = pkbf(pv[8], pv[9]),   r2d1 = pkbf(pv[10], pv[11]);
      unsigned int r3d0 = pkbf(pv[12], pv[13]), r3d1 = pkbf(pv[14], pv[15]);
      asm volatile("v_permlane32_swap_b32 %0, %1" : "+v"(r0d0), "+v"(r1d0));
      asm volatile("v_permlane32_swap_b32 %0, %1" : "+v"(r0d1), "+v"(r1d1));
      pa[tile * 2] = __builtin_bit_cast(bf16x8, (u32x4){r0d0, r0d1, r1d0, r1d1});
      asm volatile("v_permlane32_swap_b32 %0, %1" : "+v"(r2d0), "+v"(r3d0));
      asm volatile("v_permlane32_swap_b32 %0, %1" : "+v"(r2d1), "+v"(r3d1));
      pa[tile * 2 + 1] =
          __builtin_bit_cast(bf16x8, (u32x4){r2d0, r2d1, r3d0, r3d1});
    }

    __builtin_amdgcn_s_setprio(1);
#pragma unroll
    for (int kt = 0; kt < 4; ++kt) {
      int sw0 = ((kt * 2 + hi) ^ (l31 & 7)) << 3;
      bf16x8 vb0 = *(const bf16x8*)(Vs[cur] + l31 * 64 + sw0);
      bf16x8 vb1 = *(const bf16x8*)(Vs[cur] + (32 + l31) * 64 + sw0);
      oacc0 = mfma32(pa[kt], vb0, oacc0);
      oacc1 = mfma32(pa[kt], vb1, oacc1);
    }
    __builtin_amdgcn_s_setprio(0);
    asm volatile("" ::: "memory");  // keep compute's LDS reads inside step
  }

  rs += __shfl_xor(rs, 32);

  size_t zb = (size_t)(z * 16 + bh) * 2048 + q0 + w * 32;
#pragma unroll
  for (int r = 0; r < 16; ++r) {
    int ql = (r & 3) + 8 * (r >> 2) + 4 * hi;
    Op[(zb + ql) * 64 + l31] = (bf16)oacc0[r];
    Op[(zb + ql) * 64 + 32 + l31] = (bf16)oacc1[r];
  }
  if (hi == 0) {
    mbuf[zb + l31] = mrow;
    lbuf[zb + l31] = rs;
  }
}

// ---------------------------------------------------------------------------
// combine (unchanged): oh[row][d] = sum_z wz*O_z / sum_z wz*l_z.
// oh ALIASES Op[z=0] (each thread reads only its own slice -> race-free).
// ---------------------------------------------------------------------------
__global__ __launch_bounds__(256) void combine(
    const bf16* __restrict__ Op, const float* __restrict__ mbuf,
    const float* __restrict__ lbuf, bf16* __restrict__ oh, int NS) {
  int idx = blockIdx.x * 256 + threadIdx.x;
  int row = idx >> 2;
  int dc = (idx & 3) * 16;

  float M = -1e30f;
  for (int z = 0; z < NS; ++z) M = fmaxf(M, mbuf[(size_t)z * 32768 + row]);

  float L = 0.0f;
  float acc[16];
#pragma unroll
  for (int e = 0; e < 16; ++e) acc[e] = 0.0f;

  for (int z = 0; z < NS; ++z) {
    float wz = __builtin_amdgcn_exp2f(mbuf[(size_t)z * 32768 + row] - M);
    L += wz * lbuf[(size_t)z * 32768 + row];
    const bf16x8* p = (const bf16x8*)(Op + ((size_t)z * 32768 + row) * 64 + dc);
#pragma unroll
    for (int v = 0; v < 2; ++v) {
      bf16x8 x = p[v];
#pragma unroll
      for (int e = 0; e < 8; ++e) acc[v * 8 + e] += wz * (float)x[e];
    }
  }
  float invL = 1.0f / L;
  bf16x8* po = (bf16x8*)(oh + (size_t)row * 64 + dc);
#pragma unroll
  for (int v = 0; v < 2; ++v) {
    bf16x8 o;
#pragma unroll
    for (int e = 0; e < 8; ++e) o[e] = (bf16)(acc[v * 8 + e] * invL);
    po[v] = o;
  }
}

// ---------------------------------------------------------------------------
// out_gemm v6: 128x64 tile, BK=32, 16 K-steps, 4-buffer depth-2 counted
// vmcnt pipeline (R15 template). Per k-step: head hh=ks>>1, d0=(ks&1)*32.
// Same 64B-row bank swizzle as qkv v8. XCD chunk swizzle, 1-D grid 256.
// ---------------------------------------------------------------------------
__global__ __launch_bounds__(256) void out_gemm(
    const bf16* __restrict__ Wor, const bf16* __restrict__ oh,
    const float* __restrict__ bo, float* __restrict__ out) {
  __shared__ bf16 Al[4][128 * 32];
  __shared__ bf16 Bl[4][64 * 32];
  int hbid = blockIdx.x;
  int o = (hbid & 7) * 32 + (hbid >> 3);
  int r0 = (o & 3) * 128;
  int p0 = ((o >> 2) & 31) * 64;
  int b = o >> 7;
  int tid = threadIdx.x, w = tid >> 6, lane = tid & 63;
  int wm = w >> 1, wn = w & 1;
  int g = lane >> 4, l15 = lane & 15;

  const bf16* Abase = Wor + (size_t)r0 * 512;
  const bf16* Bhead = oh + ((size_t)b * 8 * 2048 + p0) * 64;

  int srow = tid >> 2;           // 0..63
  int sc = tid & 3;

  f32x4 acc[4][2] = {};

  // prologue: issue steps 0 and 1
#pragma unroll
  for (int t0 = 0; t0 < 2; ++t0) {
    int k0 = t0 * 32;
    int hh = k0 >> 6, d0 = k0 & 63;
#pragma unroll
    for (int i = 0; i < 2; ++i) {
      int row = i * 64 + srow;
      int ch = sc ^ ((row >> 1) & 3);
      gload_lds16(Abase + (size_t)row * 512 + k0 + ch * 8,
                  Al[t0] + (i * 64 + w * 16) * 32);
    }
    {
      int ch = sc ^ ((srow >> 1) & 3);
      gload_lds16(Bhead + ((size_t)hh * 2048 + srow) * 64 + d0 + ch * 8,
                  Bl[t0] + w * 16 * 32);
    }
  }

  for (int ks = 0; ks < 16; ++ks) {
    int cur = ks & 3;
    int nb = (ks + 2) & 3;
    int kq = (ks + 2 < 16) ? ks + 2 : 15;  // clamped redundant issue
    int k0n = kq * 32;
    int hhn = k0n >> 6, d0n = k0n & 63;
#pragma unroll
    for (int i = 0; i < 2; ++i) {
      int row = i * 64 + srow;
      int ch = sc ^ ((row >> 1) & 3);
      gload_lds16(Abase + (size_t)row * 512 + k0n + ch * 8,
                  Al[nb] + (i * 64 + w * 16) * 32);
    }
    {
      int ch = sc ^ ((srow >> 1) & 3);
      gload_lds16(Bhead + ((size_t)hhn * 2048 + srow) * 64 + d0n + ch * 8,
                  Bl[nb] + w * 16 * 32);
    }

    asm volatile("s_waitcnt vmcnt(6)" ::: "memory");
    __builtin_amdgcn_s_barrier();
    __builtin_amdgcn_sched_barrier(0);
    asm volatile("" ::: "memory");

    bf16x8 a[4], bb[2];
#pragma unroll
    for (int mi = 0; mi < 4; ++mi) {
      int row = wm * 64 + mi * 16 + l15;
      a[mi] = *(const bf16x8*)(Al[cur] + row * 32 +
                               ((g ^ ((row >> 1) & 3)) << 3));
    }
#pragma unroll
    for (int ni = 0; ni < 2; ++ni) {
      int row = wn * 32 + ni * 16 + l15;
      bb[ni] = *(const bf16x8*)(Bl[cur] + row * 32 +
                                ((g ^ ((row >> 1) & 3)) << 3));
    }
#pragma unroll
    for (int mi = 0; mi < 4; ++mi)
#pragma unroll
      for (int ni = 0; ni < 2; ++ni)
        acc[mi][ni] = mfma16(a[mi], bb[ni], acc[mi][ni]);
    asm volatile("" ::: "memory");
  }

#pragma unroll
  for (int mi = 0; mi < 4; ++mi) {
#pragma unroll
    for (int ni = 0; ni < 2; ++ni) {
#pragma unroll
      for (int r = 0; r < 4; ++r) {
        int row = r0 + wm * 64 + mi * 16 + g * 4 + r;
        int p = p0 + wn * 32 + ni * 16 + l15;
        out[((size_t)b * 512 + row) * 2048 + p] = acc[mi][ni][r] + bo[row];
      }
    }
  }
}

// ---------------------------------------------------------------------------
extern "C" void kernel_launch(void* const* d_in, const int* in_sizes, int n_in,
                              void* d_out, int out_size, void* d_ws, size_t ws_size,
                              hipStream_t stream) {
  (void)in_sizes; (void)n_in; (void)out_size;
  const float* Q  = (const float*)d_in[0];
  const float* Wq = (const float*)d_in[1];
  const float* bq = (const float*)d_in[2];
  const float* Wk = (const float*)d_in[3];
  const float* bk = (const float*)d_in[4];
  const float* Wv = (const float*)d_in[5];
  const float* bv = (const float*)d_in[6];
  const float* Wo = (const float*)d_in[7];
  const float* bo = (const float*)d_in[8];
  float* out = (float*)d_out;

  char* ws = (char*)d_ws;
  bf16*  Wf    = (bf16*)(ws + 0);          // 1536*512*2  = 1572864
  bf16*  Wor   = (bf16*)(ws + 1572864);    // 512*512*2   = 524288
  float* biasf = (float*)(ws + 2097152);   // 1536*4      = 6144
  bf16*  Qt    = (bf16*)(ws + 2103296);    // 2*2048*512*2 = 4194304
  bf16*  qp    = (bf16*)(ws + 6297600);    // 4194304
  bf16*  kp    = (bf16*)(ws + 10491904);   // 4194304
  bf16*  vt    = (bf16*)(ws + 14686208);   // 4194304 (ends 18880512)

  size_t need4 = 18880512ull + 4ull * 4194304 + 2ull * 4ull * 131072;
  int NS = (ws_size >= need4) ? 4 : 2;
  int TS = 32 / NS;

  bf16*  Opart = (bf16*)(ws + 18880512);               // NS * 4194304 bytes
  float* mbuf  = (float*)(ws + 18880512 + (size_t)NS * 4194304);
  float* lbuf  = (float*)(ws + 18880512 + (size_t)NS * 4194304 +
                          (size_t)NS * 131072);
  bf16*  oh    = Opart;  // combine writes in place over z=0 (race-free)

  prep<<<dim3(768), dim3(256), 0, stream>>>(Q, Wq, bq, Wk, bk, Wv, bv, Wo,
                                            Wf, biasf, Wor, Qt);
  qkv_gemm<<<dim3(768), dim3(256), 0, stream>>>(Wf, Qt, biasf, qp, kp, vt);
  attn_k<<<dim3(16 * NS * 8), dim3(512), 0, stream>>>(qp, kp, vt, Opart, mbuf,
                                                      lbuf, TS);
  combine<<<dim3(512), dim3(256), 0, stream>>>(Opart, mbuf, lbuf, oh, NS);
  out_gemm<<<dim3(256), dim3(256), 0, stream>>>(Wor, oh, bo, out);
}

// Round 18
// 69.527 us; speedup vs baseline: 1.0724x; 1.0724x over previous
//
#include <hip/hip_runtime.h>

#define DEV __device__ __forceinline__

typedef __bf16 bf16;
typedef __bf16 bf16x8 __attribute__((ext_vector_type(8)));
typedef __bf16 bf16x4 __attribute__((ext_vector_type(4)));
typedef float f32x4 __attribute__((ext_vector_type(4)));
typedef float f32x16 __attribute__((ext_vector_type(16)));
typedef unsigned int u32x4 __attribute__((ext_vector_type(4)));

// 1/sqrt(512) * log2(e): scores pre-scaled so softmax uses exp2 directly
#define SCALE_F (0.04419417382415922f * 1.4426950408889634f)

DEV void gload_lds16(const void* g, void* l) {
  __builtin_amdgcn_global_load_lds(
      (const __attribute__((address_space(1))) void*)g,
      (__attribute__((address_space(3))) void*)l, 16, 0, 0);
}

DEV f32x4 mfma16(bf16x8 a, bf16x8 b, f32x4 c) {
  return __builtin_amdgcn_mfma_f32_16x16x32_bf16(a, b, c, 0, 0, 0);
}
DEV f32x16 mfma32(bf16x8 a, bf16x8 b, f32x16 c) {
  return __builtin_amdgcn_mfma_f32_32x32x16_bf16(a, b, c, 0, 0, 0);
}

DEV unsigned int pkbf(float a, float b) {
  unsigned short ua = __builtin_bit_cast(unsigned short, (bf16)a);
  unsigned short ub = __builtin_bit_cast(unsigned short, (bf16)b);
  return (unsigned int)ua | ((unsigned int)ub << 16);
}

// ---------------------------------------------------------------------------
// prep v2 (R13): blocks 0..255 -> weight prep; 256..767 -> Q transpose.
// ---------------------------------------------------------------------------
__global__ __launch_bounds__(256) void prep(
    const float* __restrict__ Q,
    const float* __restrict__ Wq, const float* __restrict__ bq,
    const float* __restrict__ Wk, const float* __restrict__ bk,
    const float* __restrict__ Wv, const float* __restrict__ bv,
    const float* __restrict__ Wo,
    bf16* __restrict__ Wf, float* __restrict__ biasf, bf16* __restrict__ Wor,
    bf16* __restrict__ Qt) {
  __shared__ float tile[64][65];
  int bid = blockIdx.x;
  int t = threadIdx.x;
  if (bid < 256) {
    int r0 = bid * 8;
    for (int idx = t; idx < 1024; idx += 256) {  // 8 rows x 128 float4
      int rl = idx >> 7, c4 = idx & 127;
      int row = r0 + rl;
      if (row < 1536) {
        const float* src;
        float scale = 1.0f;
        if (row < 512)       { src = Wq + (size_t)row * 512; scale = SCALE_F; }
        else if (row < 1024) { src = Wk + (size_t)(row - 512) * 512; }
        else                 { src = Wv + (size_t)(row - 1024) * 512; }
        float4 v = ((const float4*)src)[c4];
        bf16x4 o;
        o[0] = (bf16)(v.x * scale);
        o[1] = (bf16)(v.y * scale);
        o[2] = (bf16)(v.z * scale);
        o[3] = (bf16)(v.w * scale);
        *(bf16x4*)(Wf + (size_t)row * 512 + c4 * 4) = o;
      } else {
        int r = row - 1536;
#pragma unroll
        for (int e = 0; e < 4; ++e) {
          int c2 = c4 * 4 + e;
          Wor[(size_t)r * 512 + c2] =
              (bf16)Wo[(size_t)r * 512 + (c2 & 63) * 8 + (c2 >> 6)];
        }
      }
    }
    if (t < 8 && r0 + t < 1536) {
      int row = r0 + t;
      float bb;
      if (row < 512)       bb = bq[row] * SCALE_F;
      else if (row < 1024) bb = bk[row - 512];
      else                 bb = bv[row - 1024];
      biasf[row] = bb;
    }
  } else {
    int id2 = bid - 256;
    int n0 = (id2 & 31) * 64;
    int d0 = ((id2 >> 5) & 7) * 64;
    int b = id2 >> 8;
    int r = t >> 2, cw = t & 3;
    const float* src = Q + ((size_t)(b * 512 + d0 + r)) * 2048 + n0 + cw * 16;
#pragma unroll
    for (int e4 = 0; e4 < 4; ++e4) {
      float4 v = *(const float4*)(src + e4 * 4);
      tile[r][cw * 16 + e4 * 4 + 0] = v.x;
      tile[r][cw * 16 + e4 * 4 + 1] = v.y;
      tile[r][cw * 16 + e4 * 4 + 2] = v.z;
      tile[r][cw * 16 + e4 * 4 + 3] = v.w;
    }
    __syncthreads();
    bf16x8 o0{}, o1{};
#pragma unroll
    for (int e = 0; e < 8; ++e) {
      o0[e] = (bf16)tile[cw * 16 + e][r];
      o1[e] = (bf16)tile[cw * 16 + 8 + e][r];
    }
    bf16* dst = Qt + ((size_t)(b * 2048 + n0 + r)) * 512 + d0 + cw * 16;
    *(bf16x8*)dst = o0;
    *((bf16x8*)dst + 1) = o1;
  }
}

// ---------------------------------------------------------------------------
// qkv_gemm v7 (R16): 128x64 tile, BK=64, XOR swizzle, XCD chunk swizzle.
// Epilogue writes qp / kp / vt (pre-tiled V). 1-D grid 768.
// ---------------------------------------------------------------------------
__global__ __launch_bounds__(256) void qkv_gemm(
    const bf16* __restrict__ Wf, const bf16* __restrict__ Qt,
    const float* __restrict__ biasf,
    bf16* __restrict__ qp, bf16* __restrict__ kp, bf16* __restrict__ vt) {
  __shared__ bf16 Al[128 * 64];
  __shared__ bf16 Bl[64 * 64];
  int hbid = blockIdx.x;
  int o = (hbid & 7) * 96 + (hbid >> 3);
  int cx = o % 12;
  int py = (o / 12) & 31;
  int b = o / 384;
  int c0 = cx * 128;
  int p0 = py * 64;
  int tid = threadIdx.x, w = tid >> 6, lane = tid & 63;
  int wm = w >> 1, wn = w & 1;
  int g = lane >> 4, l15 = lane & 15;

  const bf16* Abase = Wf + (size_t)c0 * 512;
  const bf16* Bbase = Qt + ((size_t)b * 2048 + p0) * 512;

  int srow = tid >> 3;           // 0..31 (+i*32)
  int sch = tid & 7;

  f32x4 acc[4][2] = {};

  for (int ks = 0; ks < 8; ++ks) {
    int k0 = ks * 64;
    __syncthreads();
#pragma unroll
    for (int i = 0; i < 4; ++i) {
      int row = srow + i * 32;
      int ch = sch ^ (row & 7);
      gload_lds16(Abase + (size_t)row * 512 + k0 + ch * 8,
                  Al + (i * 32 + w * 8) * 64);
    }
#pragma unroll
    for (int i = 0; i < 2; ++i) {
      int row = srow + i * 32;
      int ch = sch ^ (row & 7);
      gload_lds16(Bbase + (size_t)row * 512 + k0 + ch * 8,
                  Bl + (i * 32 + w * 8) * 64);
    }
    __syncthreads();
#pragma unroll
    for (int ks2 = 0; ks2 < 2; ++ks2) {
      bf16x8 a[4], bb[2];
#pragma unroll
      for (int mi = 0; mi < 4; ++mi) {
        int row = wm * 64 + mi * 16 + l15;
        a[mi] = *(const bf16x8*)(Al + row * 64 +
                                 (((ks2 * 4 + g) ^ (row & 7)) << 3));
      }
#pragma unroll
      for (int ni = 0; ni < 2; ++ni) {
        int row = wn * 32 + ni * 16 + l15;
        bb[ni] = *(const bf16x8*)(Bl + row * 64 +
                                  (((ks2 * 4 + g) ^ (row & 7)) << 3));
      }
#pragma unroll
      for (int mi = 0; mi < 4; ++mi)
#pragma unroll
        for (int ni = 0; ni < 2; ++ni)
          acc[mi][ni] = mfma16(a[mi], bb[ni], acc[mi][ni]);
    }
  }

#pragma unroll
  for (int mi = 0; mi < 4; ++mi) {
#pragma unroll
    for (int ni = 0; ni < 2; ++ni) {
#pragma unroll
      for (int r = 0; r < 4; ++r) {
        int row = c0 + wm * 64 + mi * 16 + g * 4 + r;
        int p = p0 + wn * 32 + ni * 16 + l15;
        float val = acc[mi][ni][r] + biasf[row];
        bf16 hv = (bf16)val;
        if (row < 512) {
          int c = row;
          qp[(((size_t)b * 8 + (c & 7)) * 2048 + p) * 64 + (c >> 3)] = hv;
        } else if (row < 1024) {
          int c = row - 512;
          kp[(((size_t)b * 8 + (c & 7)) * 2048 + p) * 64 + (c >> 3)] = hv;
        } else {
          int c = row - 1024;       // c = d*8 + h
          int d = c >> 3, hh = c & 7;
          vt[((((size_t)b * 8 + hh) * 32 + (p >> 6)) * 64 + d) * 64 +
             (p & 63)] = hv;
        }
      }
    }
  }
}

// ---------------------------------------------------------------------------
// attn_k v12 (R16): counted-vmcnt depth-2 pipeline, pre-tiled V,
// in-register P (32x32 MFMA + permlane32_swap), XCD swizzle.
// ---------------------------------------------------------------------------
__global__ __launch_bounds__(512, 4) void attn_k(
    const bf16* __restrict__ qp, const bf16* __restrict__ kp,
    const bf16* __restrict__ vt, bf16* __restrict__ Op,
    float* __restrict__ mbuf, float* __restrict__ lbuf, int TS) {
  __shared__ bf16 Ks[4][64 * 64];
  __shared__ bf16 Vs[4][64 * 64];
  int hbid = blockIdx.x;
  int o = (hbid & 7) * 64 + (hbid >> 3);
  int q0 = (o & 7) * 256;
  int bh = (o >> 3) & 15;
  int z = o >> 7;
  int tid = threadIdx.x, w = tid >> 6, lane = tid & 63;
  int l31 = lane & 31, hi = lane >> 5;

  bf16x8 qreg[4];
#pragma unroll
  for (int kd = 0; kd < 4; ++kd)
    qreg[kd] = *(const bf16x8*)(
        qp + ((size_t)bh * 2048 + q0 + w * 32 + l31) * 64 + kd * 16 + hi * 8);

  int krow = tid >> 3;            // 0..63
  int kch = (tid & 7) ^ (krow & 7);

  const bf16* Kall = kp + (size_t)bh * 2048 * 64 + (size_t)z * TS * 4096;
  const bf16* Vall = vt + ((size_t)bh * 32 + (size_t)z * TS) * 4096;

  // prologue: issue steps 0 and 1 (TS >= 8 always)
  gload_lds16(Kall + (size_t)krow * 64 + kch * 8, Ks[0] + w * 512);
  gload_lds16(Vall + (size_t)krow * 64 + kch * 8, Vs[0] + w * 512);
  gload_lds16(Kall + 4096 + (size_t)krow * 64 + kch * 8, Ks[1] + w * 512);
  gload_lds16(Vall + 4096 + (size_t)krow * 64 + kch * 8, Vs[1] + w * 512);

  f32x16 oacc0 = {}, oacc1 = {};
  float mrow = -1e30f, rs = 0.0f;

  for (int t = 0; t < TS; ++t) {
    int cur = t & 3;
    int nb = (t + 2) & 3;
    int tp = (t + 2 < TS) ? t + 2 : TS - 1;  // clamped redundant issue

    gload_lds16(Kall + (size_t)tp * 4096 + (size_t)krow * 64 + kch * 8,
                Ks[nb] + w * 512);
    gload_lds16(Vall + (size_t)tp * 4096 + (size_t)krow * 64 + kch * 8,
                Vs[nb] + w * 512);

    // wait for step-t's pair (oldest 2 of 6 outstanding), then rendezvous
    asm volatile("s_waitcnt vmcnt(4)" ::: "memory");
    __builtin_amdgcn_s_barrier();
    __builtin_amdgcn_sched_barrier(0);
    asm volatile("" ::: "memory");

    f32x16 st0 = {}, st1 = {};
    __builtin_amdgcn_s_setprio(1);
#pragma unroll
    for (int kd = 0; kd < 4; ++kd) {
      int sw = ((kd * 2 + hi) ^ (l31 & 7)) << 3;
      bf16x8 kb0 = *(const bf16x8*)(Ks[cur] + l31 * 64 + sw);
      bf16x8 kb1 = *(const bf16x8*)(Ks[cur] + (32 + l31) * 64 + sw);
      st0 = mfma32(kb0, qreg[kd], st0);
      st1 = mfma32(kb1, qreg[kd], st1);
    }
    __builtin_amdgcn_s_setprio(0);

    float rm = st0[0];
#pragma unroll
    for (int r = 1; r < 16; ++r) rm = fmaxf(rm, st0[r]);
#pragma unroll
    for (int r = 0; r < 16; ++r) rm = fmaxf(rm, st1[r]);
    rm = fmaxf(rm, __shfl_xor(rm, 32));

    if (__any(rm > mrow + 8.0f)) {
      float nm = fmaxf(mrow, rm);
      float esc = __builtin_amdgcn_exp2f(mrow - nm);
      mrow = nm;
      rs *= esc;
#pragma unroll
      for (int r = 0; r < 16; ++r) {
        int ql = (r & 3) + 8 * (r >> 2) + 4 * hi;
        float er = __shfl(esc, ql, 64);
        oacc0[r] *= er;
        oacc1[r] *= er;
      }
    }

    bf16x8 pa[4];
#pragma unroll
    for (int tile = 0; tile < 2; ++tile) {
      float pv[16];
#pragma unroll
      for (int r = 0; r < 16; ++r) {
        float v = __builtin_amdgcn_exp2f((tile ? st1[r] : st0[r]) - mrow);
        pv[r] = v;
        rs += v;
      }
      unsigned int r0d0 = pkbf(pv[0], pv[1]),   r0d1 = pkbf(pv[2], pv[3]);
      unsigned int r1d0 = pkbf(pv[4], pv[5]),   r1d1 = pkbf(pv[6], pv[7]);
      unsigned int r2d0 = pkbf(pv[8], pv[9]),   r2d1 = pkbf(pv[10], pv[11]);
      unsigned int r3d0 = pkbf(pv[12], pv[13]), r3d1 = pkbf(pv[14], pv[15]);
      asm volatile("v_permlane32_swap_b32 %0, %1" : "+v"(r0d0), "+v"(r1d0));
      asm volatile("v_permlane32_swap_b32 %0, %1" : "+v"(r0d1), "+v"(r1d1));
      pa[tile * 2] = __builtin_bit_cast(bf16x8, (u32x4){r0d0, r0d1, r1d0, r1d1});
      asm volatile("v_permlane32_swap_b32 %0, %1" : "+v"(r2d0), "+v"(r3d0));
      asm volatile("v_permlane32_swap_b32 %0, %1" : "+v"(r2d1), "+v"(r3d1));
      pa[tile * 2 + 1] =
          __builtin_bit_cast(bf16x8, (u32x4){r2d0, r2d1, r3d0, r3d1});
    }

    __builtin_amdgcn_s_setprio(1);
#pragma unroll
    for (int kt = 0; kt < 4; ++kt) {
      int sw0 = ((kt * 2 + hi) ^ (l31 & 7)) << 3;
      bf16x8 vb0 = *(const bf16x8*)(Vs[cur] + l31 * 64 + sw0);
      bf16x8 vb1 = *(const bf16x8*)(Vs[cur] + (32 + l31) * 64 + sw0);
      oacc0 = mfma32(pa[kt], vb0, oacc0);
      oacc1 = mfma32(pa[kt], vb1, oacc1);
    }
    __builtin_amdgcn_s_setprio(0);
    asm volatile("" ::: "memory");  // keep compute's LDS reads inside step
  }

  rs += __shfl_xor(rs, 32);

  size_t zb = (size_t)(z * 16 + bh) * 2048 + q0 + w * 32;
#pragma unroll
  for (int r = 0; r < 16; ++r) {
    int ql = (r & 3) + 8 * (r >> 2) + 4 * hi;
    Op[(zb + ql) * 64 + l31] = (bf16)oacc0[r];
    Op[(zb + ql) * 64 + 32 + l31] = (bf16)oacc1[r];
  }
  if (hi == 0) {
    mbuf[zb + l31] = mrow;
    lbuf[zb + l31] = rs;
  }
}

// ---------------------------------------------------------------------------
// combine (unchanged): oh[row][d] = sum_z wz*O_z / sum_z wz*l_z.
// oh ALIASES Op[z=0] (each thread reads only its own slice -> race-free).
// ---------------------------------------------------------------------------
__global__ __launch_bounds__(256) void combine(
    const bf16* __restrict__ Op, const float* __restrict__ mbuf,
    const float* __restrict__ lbuf, bf16* __restrict__ oh, int NS) {
  int idx = blockIdx.x * 256 + threadIdx.x;
  int row = idx >> 2;
  int dc = (idx & 3) * 16;

  float M = -1e30f;
  for (int z = 0; z < NS; ++z) M = fmaxf(M, mbuf[(size_t)z * 32768 + row]);

  float L = 0.0f;
  float acc[16];
#pragma unroll
  for (int e = 0; e < 16; ++e) acc[e] = 0.0f;

  for (int z = 0; z < NS; ++z) {
    float wz = __builtin_amdgcn_exp2f(mbuf[(size_t)z * 32768 + row] - M);
    L += wz * lbuf[(size_t)z * 32768 + row];
    const bf16x8* p = (const bf16x8*)(Op + ((size_t)z * 32768 + row) * 64 + dc);
#pragma unroll
    for (int v = 0; v < 2; ++v) {
      bf16x8 x = p[v];
#pragma unroll
      for (int e = 0; e < 8; ++e) acc[v * 8 + e] += wz * (float)x[e];
    }
  }
  float invL = 1.0f / L;
  bf16x8* po = (bf16x8*)(oh + (size_t)row * 64 + dc);
#pragma unroll
  for (int v = 0; v < 2; ++v) {
    bf16x8 o;
#pragma unroll
    for (int e = 0; e < 8; ++e) o[e] = (bf16)(acc[v * 8 + e] * invL);
    po[v] = o;
  }
}

// ---------------------------------------------------------------------------
// out_gemm v7: 64x64 tile, BK=64 (one head per K-step), grid 512 = 2/CU
// (was 256 = 1/CU). XCD chunk swizzle. 4 waves 2x2. XOR-chunk swizzle.
// ISOLATED CHANGE vs R16: any total delta vs 71.0 attributes here.
// ---------------------------------------------------------------------------
__global__ __launch_bounds__(256) void out_gemm(
    const bf16* __restrict__ Wor, const bf16* __restrict__ oh,
    const float* __restrict__ bo, float* __restrict__ out) {
  __shared__ bf16 Al[64 * 64];
  __shared__ bf16 Bl[64 * 64];
  int hbid = blockIdx.x;
  int o = (hbid & 7) * 64 + (hbid >> 3);
  int b = o >> 8;
  int r = o & 255;
  int rx = r >> 5;               // 0..7
  int py = r & 31;
  int r0 = rx * 64;
  int p0 = py * 64;
  int tid = threadIdx.x, w = tid >> 6, lane = tid & 63;
  int wm = w >> 1, wn = w & 1;
  int g = lane >> 4, l15 = lane & 15;

  const bf16* Abase = Wor + (size_t)r0 * 512;

  int srow = tid >> 3;
  int sch = tid & 7;

  f32x4 acc[2][2] = {};

  for (int ks = 0; ks < 8; ++ks) {
    int k0 = ks * 64;
    const bf16* Bbase = oh + (((size_t)b * 8 + ks) * 2048 + p0) * 64;
    __syncthreads();
#pragma unroll
    for (int i = 0; i < 2; ++i) {
      int row = srow + i * 32;
      int ch = sch ^ (row & 7);
      gload_lds16(Abase + (size_t)row * 512 + k0 + ch * 8,
                  Al + (i * 32 + w * 8) * 64);
      gload_lds16(Bbase + (size_t)row * 64 + ch * 8,
                  Bl + (i * 32 + w * 8) * 64);
    }
    __syncthreads();
#pragma unroll
    for (int ks2 = 0; ks2 < 2; ++ks2) {
      bf16x8 a[2], bb[2];
#pragma unroll
      for (int mi = 0; mi < 2; ++mi) {
        int row = wm * 32 + mi * 16 + l15;
        a[mi] = *(const bf16x8*)(Al + row * 64 +
                                 (((ks2 * 4 + g) ^ (row & 7)) << 3));
      }
#pragma unroll
      for (int ni = 0; ni < 2; ++ni) {
        int row = wn * 32 + ni * 16 + l15;
        bb[ni] = *(const bf16x8*)(Bl + row * 64 +
                                  (((ks2 * 4 + g) ^ (row & 7)) << 3));
      }
#pragma unroll
      for (int mi = 0; mi < 2; ++mi)
#pragma unroll
        for (int ni = 0; ni < 2; ++ni)
          acc[mi][ni] = mfma16(a[mi], bb[ni], acc[mi][ni]);
    }
  }

#pragma unroll
  for (int mi = 0; mi < 2; ++mi) {
#pragma unroll
    for (int ni = 0; ni < 2; ++ni) {
#pragma unroll
      for (int r2 = 0; r2 < 4; ++r2) {
        int row = r0 + wm * 32 + mi * 16 + g * 4 + r2;
        int p = p0 + wn * 32 + ni * 16 + l15;
        out[((size_t)b * 512 + row) * 2048 + p] = acc[mi][ni][r2] + bo[row];
      }
    }
  }
}

// ---------------------------------------------------------------------------
extern "C" void kernel_launch(void* const* d_in, const int* in_sizes, int n_in,
                              void* d_out, int out_size, void* d_ws, size_t ws_size,
                              hipStream_t stream) {
  (void)in_sizes; (void)n_in; (void)out_size;
  const float* Q  = (const float*)d_in[0];
  const float* Wq = (const float*)d_in[1];
  const float* bq = (const float*)d_in[2];
  const float* Wk = (const float*)d_in[3];
  const float* bk = (const float*)d_in[4];
  const float* Wv = (const float*)d_in[5];
  const float* bv = (const float*)d_in[6];
  const float* Wo = (const float*)d_in[7];
  const float* bo = (const float*)d_in[8];
  float* out = (float*)d_out;

  char* ws = (char*)d_ws;
  bf16*  Wf    = (bf16*)(ws + 0);          // 1536*512*2  = 1572864
  bf16*  Wor   = (bf16*)(ws + 1572864);    // 512*512*2   = 524288
  float* biasf = (float*)(ws + 2097152);   // 1536*4      = 6144
  bf16*  Qt    = (bf16*)(ws + 2103296);    // 2*2048*512*2 = 4194304
  bf16*  qp    = (bf16*)(ws + 6297600);    // 4194304
  bf16*  kp    = (bf16*)(ws + 10491904);   // 4194304
  bf16*  vt    = (bf16*)(ws + 14686208);   // 4194304 (ends 18880512)

  size_t need4 = 18880512ull + 4ull * 4194304 + 2ull * 4ull * 131072;
  int NS = (ws_size >= need4) ? 4 : 2;
  int TS = 32 / NS;

  bf16*  Opart = (bf16*)(ws + 18880512);               // NS * 4194304 bytes
  float* mbuf  = (float*)(ws + 18880512 + (size_t)NS * 4194304);
  float* lbuf  = (float*)(ws + 18880512 + (size_t)NS * 4194304 +
                          (size_t)NS * 131072);
  bf16*  oh    = Opart;  // combine writes in place over z=0 (race-free)

  prep<<<dim3(768), dim3(256), 0, stream>>>(Q, Wq, bq, Wk, bk, Wv, bv, Wo,
                                            Wf, biasf, Wor, Qt);
  qkv_gemm<<<dim3(768), dim3(256), 0, stream>>>(Wf, Qt, biasf, qp, kp, vt);
  attn_k<<<dim3(16 * NS * 8), dim3(512), 0, stream>>>(qp, kp, vt, Opart, mbuf,
                                                      lbuf, TS);
  combine<<<dim3(512), dim3(256), 0, stream>>>(Opart, mbuf, lbuf, oh, NS);
  out_gemm<<<dim3(512), dim3(256), 0, stream>>>(Wor, oh, bo, out);
}

// Round 19
// 69.138 us; speedup vs baseline: 1.0785x; 1.0056x over previous
//
#include <hip/hip_runtime.h>

#define DEV __device__ __forceinline__

typedef __bf16 bf16;
typedef __bf16 bf16x8 __attribute__((ext_vector_type(8)));
typedef __bf16 bf16x4 __attribute__((ext_vector_type(4)));
typedef float f32x4 __attribute__((ext_vector_type(4)));
typedef float f32x16 __attribute__((ext_vector_type(16)));
typedef unsigned int u32x4 __attribute__((ext_vector_type(4)));

// 1/sqrt(512) * log2(e): scores pre-scaled so softmax uses exp2 directly
#define SCALE_F (0.04419417382415922f * 1.4426950408889634f)

DEV void gload_lds16(const void* g, void* l) {
  __builtin_amdgcn_global_load_lds(
      (const __attribute__((address_space(1))) void*)g,
      (__attribute__((address_space(3))) void*)l, 16, 0, 0);
}

DEV f32x4 mfma16(bf16x8 a, bf16x8 b, f32x4 c) {
  return __builtin_amdgcn_mfma_f32_16x16x32_bf16(a, b, c, 0, 0, 0);
}
DEV f32x16 mfma32(bf16x8 a, bf16x8 b, f32x16 c) {
  return __builtin_amdgcn_mfma_f32_32x32x16_bf16(a, b, c, 0, 0, 0);
}

DEV unsigned int pkbf(float a, float b) {
  unsigned short ua = __builtin_bit_cast(unsigned short, (bf16)a);
  unsigned short ub = __builtin_bit_cast(unsigned short, (bf16)b);
  return (unsigned int)ua | ((unsigned int)ub << 16);
}

// ---------------------------------------------------------------------------
// prep v3: blocks 0..255 -> weight prep; 256..767 -> Q transpose.
// Wor part now reads Wo with COALESCED float4 (scattered 2B writes instead
// of gathered reads): Wo col j = d*8+h  ->  Wor col = (j&7)*64 + (j>>3).
// ---------------------------------------------------------------------------
__global__ __launch_bounds__(256) void prep(
    const float* __restrict__ Q,
    const float* __restrict__ Wq, const float* __restrict__ bq,
    const float* __restrict__ Wk, const float* __restrict__ bk,
    const float* __restrict__ Wv, const float* __restrict__ bv,
    const float* __restrict__ Wo,
    bf16* __restrict__ Wf, float* __restrict__ biasf, bf16* __restrict__ Wor,
    bf16* __restrict__ Qt) {
  __shared__ float tile[64][65];
  int bid = blockIdx.x;
  int t = threadIdx.x;
  if (bid < 256) {
    int r0 = bid * 8;
    for (int idx = t; idx < 1024; idx += 256) {  // 8 rows x 128 float4
      int rl = idx >> 7, c4 = idx & 127;
      int row = r0 + rl;
      if (row < 1536) {
        const float* src;
        float scale = 1.0f;
        if (row < 512)       { src = Wq + (size_t)row * 512; scale = SCALE_F; }
        else if (row < 1024) { src = Wk + (size_t)(row - 512) * 512; }
        else                 { src = Wv + (size_t)(row - 1024) * 512; }
        float4 v = ((const float4*)src)[c4];
        bf16x4 o;
        o[0] = (bf16)(v.x * scale);
        o[1] = (bf16)(v.y * scale);
        o[2] = (bf16)(v.z * scale);
        o[3] = (bf16)(v.w * scale);
        *(bf16x4*)(Wf + (size_t)row * 512 + c4 * 4) = o;
      } else {
        int r = row - 1536;
        // coalesced read of Wo, scatter-write to Wor
        float4 v = ((const float4*)(Wo + (size_t)r * 512))[c4];
        float vv[4] = {v.x, v.y, v.z, v.w};
#pragma unroll
        for (int e = 0; e < 4; ++e) {
          int j = c4 * 4 + e;                 // Wo col = d*8+h
          int dst = (j & 7) * 64 + (j >> 3);  // Wor col = h*64+d
          Wor[(size_t)r * 512 + dst] = (bf16)vv[e];
        }
      }
    }
    if (t < 8 && r0 + t < 1536) {
      int row = r0 + t;
      float bb;
      if (row < 512)       bb = bq[row] * SCALE_F;
      else if (row < 1024) bb = bk[row - 512];
      else                 bb = bv[row - 1024];
      biasf[row] = bb;
    }
  } else {
    int id2 = bid - 256;
    int n0 = (id2 & 31) * 64;
    int d0 = ((id2 >> 5) & 7) * 64;
    int b = id2 >> 8;
    int r = t >> 2, cw = t & 3;
    const float* src = Q + ((size_t)(b * 512 + d0 + r)) * 2048 + n0 + cw * 16;
#pragma unroll
    for (int e4 = 0; e4 < 4; ++e4) {
      float4 v = *(const float4*)(src + e4 * 4);
      tile[r][cw * 16 + e4 * 4 + 0] = v.x;
      tile[r][cw * 16 + e4 * 4 + 1] = v.y;
      tile[r][cw * 16 + e4 * 4 + 2] = v.z;
      tile[r][cw * 16 + e4 * 4 + 3] = v.w;
    }
    __syncthreads();
    bf16x8 o0{}, o1{};
#pragma unroll
    for (int e = 0; e < 8; ++e) {
      o0[e] = (bf16)tile[cw * 16 + e][r];
      o1[e] = (bf16)tile[cw * 16 + 8 + e][r];
    }
    bf16* dst = Qt + ((size_t)(b * 2048 + n0 + r)) * 512 + d0 + cw * 16;
    *(bf16x8*)dst = o0;
    *((bf16x8*)dst + 1) = o1;
  }
}

// ---------------------------------------------------------------------------
// qkv_gemm v7 (R16/R18): 128x64 tile, BK=64, XOR swizzle, XCD chunk swizzle.
// Epilogue writes qp / kp / vt (pre-tiled V). 1-D grid 768.
// ---------------------------------------------------------------------------
__global__ __launch_bounds__(256) void qkv_gemm(
    const bf16* __restrict__ Wf, const bf16* __restrict__ Qt,
    const float* __restrict__ biasf,
    bf16* __restrict__ qp, bf16* __restrict__ kp, bf16* __restrict__ vt) {
  __shared__ bf16 Al[128 * 64];
  __shared__ bf16 Bl[64 * 64];
  int hbid = blockIdx.x;
  int o = (hbid & 7) * 96 + (hbid >> 3);
  int cx = o % 12;
  int py = (o / 12) & 31;
  int b = o / 384;
  int c0 = cx * 128;
  int p0 = py * 64;
  int tid = threadIdx.x, w = tid >> 6, lane = tid & 63;
  int wm = w >> 1, wn = w & 1;
  int g = lane >> 4, l15 = lane & 15;

  const bf16* Abase = Wf + (size_t)c0 * 512;
  const bf16* Bbase = Qt + ((size_t)b * 2048 + p0) * 512;

  int srow = tid >> 3;           // 0..31 (+i*32)
  int sch = tid & 7;

  f32x4 acc[4][2] = {};

  for (int ks = 0; ks < 8; ++ks) {
    int k0 = ks * 64;
    __syncthreads();
#pragma unroll
    for (int i = 0; i < 4; ++i) {
      int row = srow + i * 32;
      int ch = sch ^ (row & 7);
      gload_lds16(Abase + (size_t)row * 512 + k0 + ch * 8,
                  Al + (i * 32 + w * 8) * 64);
    }
#pragma unroll
    for (int i = 0; i < 2; ++i) {
      int row = srow + i * 32;
      int ch = sch ^ (row & 7);
      gload_lds16(Bbase + (size_t)row * 512 + k0 + ch * 8,
                  Bl + (i * 32 + w * 8) * 64);
    }
    __syncthreads();
#pragma unroll
    for (int ks2 = 0; ks2 < 2; ++ks2) {
      bf16x8 a[4], bb[2];
#pragma unroll
      for (int mi = 0; mi < 4; ++mi) {
        int row = wm * 64 + mi * 16 + l15;
        a[mi] = *(const bf16x8*)(Al + row * 64 +
                                 (((ks2 * 4 + g) ^ (row & 7)) << 3));
      }
#pragma unroll
      for (int ni = 0; ni < 2; ++ni) {
        int row = wn * 32 + ni * 16 + l15;
        bb[ni] = *(const bf16x8*)(Bl + row * 64 +
                                  (((ks2 * 4 + g) ^ (row & 7)) << 3));
      }
#pragma unroll
      for (int mi = 0; mi < 4; ++mi)
#pragma unroll
        for (int ni = 0; ni < 2; ++ni)
          acc[mi][ni] = mfma16(a[mi], bb[ni], acc[mi][ni]);
    }
  }

#pragma unroll
  for (int mi = 0; mi < 4; ++mi) {
#pragma unroll
    for (int ni = 0; ni < 2; ++ni) {
#pragma unroll
      for (int r = 0; r < 4; ++r) {
        int row = c0 + wm * 64 + mi * 16 + g * 4 + r;
        int p = p0 + wn * 32 + ni * 16 + l15;
        float val = acc[mi][ni][r] + biasf[row];
        bf16 hv = (bf16)val;
        if (row < 512) {
          int c = row;
          qp[(((size_t)b * 8 + (c & 7)) * 2048 + p) * 64 + (c >> 3)] = hv;
        } else if (row < 1024) {
          int c = row - 512;
          kp[(((size_t)b * 8 + (c & 7)) * 2048 + p) * 64 + (c >> 3)] = hv;
        } else {
          int c = row - 1024;       // c = d*8 + h
          int d = c >> 3, hh = c & 7;
          vt[((((size_t)b * 8 + hh) * 32 + (p >> 6)) * 64 + d) * 64 +
             (p & 63)] = hv;
        }
      }
    }
  }
}

// ---------------------------------------------------------------------------
// attn_k v12 (R16/R18): counted-vmcnt depth-2 pipeline, pre-tiled V,
// in-register P (32x32 MFMA + permlane32_swap), XCD swizzle.
// ---------------------------------------------------------------------------
__global__ __launch_bounds__(512, 4) void attn_k(
    const bf16* __restrict__ qp, const bf16* __restrict__ kp,
    const bf16* __restrict__ vt, bf16* __restrict__ Op,
    float* __restrict__ mbuf, float* __restrict__ lbuf, int TS) {
  __shared__ bf16 Ks[4][64 * 64];
  __shared__ bf16 Vs[4][64 * 64];
  int hbid = blockIdx.x;
  int o = (hbid & 7) * 64 + (hbid >> 3);
  int q0 = (o & 7) * 256;
  int bh = (o >> 3) & 15;
  int z = o >> 7;
  int tid = threadIdx.x, w = tid >> 6, lane = tid & 63;
  int l31 = lane & 31, hi = lane >> 5;

  bf16x8 qreg[4];
#pragma unroll
  for (int kd = 0; kd < 4; ++kd)
    qreg[kd] = *(const bf16x8*)(
        qp + ((size_t)bh * 2048 + q0 + w * 32 + l31) * 64 + kd * 16 + hi * 8);

  int krow = tid >> 3;            // 0..63
  int kch = (tid & 7) ^ (krow & 7);

  const bf16* Kall = kp + (size_t)bh * 2048 * 64 + (size_t)z * TS * 4096;
  const bf16* Vall = vt + ((size_t)bh * 32 + (size_t)z * TS) * 4096;

  // prologue: issue steps 0 and 1 (TS >= 8 always)
  gload_lds16(Kall + (size_t)krow * 64 + kch * 8, Ks[0] + w * 512);
  gload_lds16(Vall + (size_t)krow * 64 + kch * 8, Vs[0] + w * 512);
  gload_lds16(Kall + 4096 + (size_t)krow * 64 + kch * 8, Ks[1] + w * 512);
  gload_lds16(Vall + 4096 + (size_t)krow * 64 + kch * 8, Vs[1] + w * 512);

  f32x16 oacc0 = {}, oacc1 = {};
  float mrow = -1e30f, rs = 0.0f;

  for (int t = 0; t < TS; ++t) {
    int cur = t & 3;
    int nb = (t + 2) & 3;
    int tp = (t + 2 < TS) ? t + 2 : TS - 1;  // clamped redundant issue

    gload_lds16(Kall + (size_t)tp * 4096 + (size_t)krow * 64 + kch * 8,
                Ks[nb] + w * 512);
    gload_lds16(Vall + (size_t)tp * 4096 + (size_t)krow * 64 + kch * 8,
                Vs[nb] + w * 512);

    // wait for step-t's pair (oldest 2 of 6 outstanding), then rendezvous
    asm volatile("s_waitcnt vmcnt(4)" ::: "memory");
    __builtin_amdgcn_s_barrier();
    __builtin_amdgcn_sched_barrier(0);
    asm volatile("" ::: "memory");

    f32x16 st0 = {}, st1 = {};
    __builtin_amdgcn_s_setprio(1);
#pragma unroll
    for (int kd = 0; kd < 4; ++kd) {
      int sw = ((kd * 2 + hi) ^ (l31 & 7)) << 3;
      bf16x8 kb0 = *(const bf16x8*)(Ks[cur] + l31 * 64 + sw);
      bf16x8 kb1 = *(const bf16x8*)(Ks[cur] + (32 + l31) * 64 + sw);
      st0 = mfma32(kb0, qreg[kd], st0);
      st1 = mfma32(kb1, qreg[kd], st1);
    }
    __builtin_amdgcn_s_setprio(0);

    float rm = st0[0];
#pragma unroll
    for (int r = 1; r < 16; ++r) rm = fmaxf(rm, st0[r]);
#pragma unroll
    for (int r = 0; r < 16; ++r) rm = fmaxf(rm, st1[r]);
    rm = fmaxf(rm, __shfl_xor(rm, 32));

    if (__any(rm > mrow + 8.0f)) {
      float nm = fmaxf(mrow, rm);
      float esc = __builtin_amdgcn_exp2f(mrow - nm);
      mrow = nm;
      rs *= esc;
#pragma unroll
      for (int r = 0; r < 16; ++r) {
        int ql = (r & 3) + 8 * (r >> 2) + 4 * hi;
        float er = __shfl(esc, ql, 64);
        oacc0[r] *= er;
        oacc1[r] *= er;
      }
    }

    bf16x8 pa[4];
#pragma unroll
    for (int tile = 0; tile < 2; ++tile) {
      float pv[16];
#pragma unroll
      for (int r = 0; r < 16; ++r) {
        float v = __builtin_amdgcn_exp2f((tile ? st1[r] : st0[r]) - mrow);
        pv[r] = v;
        rs += v;
      }
      unsigned int r0d0 = pkbf(pv[0], pv[1]),   r0d1 = pkbf(pv[2], pv[3]);
      unsigned int r1d0 = pkbf(pv[4], pv[5]),   r1d1 = pkbf(pv[6], pv[7]);
      unsigned int r2d0 = pkbf(pv[8], pv[9]),   r2d1 = pkbf(pv[10], pv[11]);
      unsigned int r3d0 = pkbf(pv[12], pv[13]), r3d1 = pkbf(pv[14], pv[15]);
      asm volatile("v_permlane32_swap_b32 %0, %1" : "+v"(r0d0), "+v"(r1d0));
      asm volatile("v_permlane32_swap_b32 %0, %1" : "+v"(r0d1), "+v"(r1d1));
      pa[tile * 2] = __builtin_bit_cast(bf16x8, (u32x4){r0d0, r0d1, r1d0, r1d1});
      asm volatile("v_permlane32_swap_b32 %0, %1" : "+v"(r2d0), "+v"(r3d0));
      asm volatile("v_permlane32_swap_b32 %0, %1" : "+v"(r2d1), "+v"(r3d1));
      pa[tile * 2 + 1] =
          __builtin_bit_cast(bf16x8, (u32x4){r2d0, r2d1, r3d0, r3d1});
    }

    __builtin_amdgcn_s_setprio(1);
#pragma unroll
    for (int kt = 0; kt < 4; ++kt) {
      int sw0 = ((kt * 2 + hi) ^ (l31 & 7)) << 3;
      bf16x8 vb0 = *(const bf16x8*)(Vs[cur] + l31 * 64 + sw0);
      bf16x8 vb1 = *(const bf16x8*)(Vs[cur] + (32 + l31) * 64 + sw0);
      oacc0 = mfma32(pa[kt], vb0, oacc0);
      oacc1 = mfma32(pa[kt], vb1, oacc1);
    }
    __builtin_amdgcn_s_setprio(0);
    asm volatile("" ::: "memory");  // keep compute's LDS reads inside step
  }

  rs += __shfl_xor(rs, 32);

  size_t zb = (size_t)(z * 16 + bh) * 2048 + q0 + w * 32;
#pragma unroll
  for (int r = 0; r < 16; ++r) {
    int ql = (r & 3) + 8 * (r >> 2) + 4 * hi;
    Op[(zb + ql) * 64 + l31] = (bf16)oacc0[r];
    Op[(zb + ql) * 64 + 32 + l31] = (bf16)oacc1[r];
  }
  if (hi == 0) {
    mbuf[zb + l31] = mrow;
    lbuf[zb + l31] = rs;
  }
}

// ---------------------------------------------------------------------------
// combine (unchanged): oh[row][d] = sum_z wz*O_z / sum_z wz*l_z.
// oh ALIASES Op[z=0] (each thread reads only its own slice -> race-free).
// ---------------------------------------------------------------------------
__global__ __launch_bounds__(256) void combine(
    const bf16* __restrict__ Op, const float* __restrict__ mbuf,
    const float* __restrict__ lbuf, bf16* __restrict__ oh, int NS) {
  int idx = blockIdx.x * 256 + threadIdx.x;
  int row = idx >> 2;
  int dc = (idx & 3) * 16;

  float M = -1e30f;
  for (int z = 0; z < NS; ++z) M = fmaxf(M, mbuf[(size_t)z * 32768 + row]);

  float L = 0.0f;
  float acc[16];
#pragma unroll
  for (int e = 0; e < 16; ++e) acc[e] = 0.0f;

  for (int z = 0; z < NS; ++z) {
    float wz = __builtin_amdgcn_exp2f(mbuf[(size_t)z * 32768 + row] - M);
    L += wz * lbuf[(size_t)z * 32768 + row];
    const bf16x8* p = (const bf16x8*)(Op + ((size_t)z * 32768 + row) * 64 + dc);
#pragma unroll
    for (int v = 0; v < 2; ++v) {
      bf16x8 x = p[v];
#pragma unroll
      for (int e = 0; e < 8; ++e) acc[v * 8 + e] += wz * (float)x[e];
    }
  }
  float invL = 1.0f / L;
  bf16x8* po = (bf16x8*)(oh + (size_t)row * 64 + dc);
#pragma unroll
  for (int v = 0; v < 2; ++v) {
    bf16x8 o;
#pragma unroll
    for (int e = 0; e < 8; ++e) o[e] = (bf16)(acc[v * 8 + e] * invL);
    po[v] = o;
  }
}

// ---------------------------------------------------------------------------
// out_gemm v7 (R18): 64x64 tile, BK=64, grid 512 = 2/CU, XCD chunk swizzle.
// ---------------------------------------------------------------------------
__global__ __launch_bounds__(256) void out_gemm(
    const bf16* __restrict__ Wor, const bf16* __restrict__ oh,
    const float* __restrict__ bo, float* __restrict__ out) {
  __shared__ bf16 Al[64 * 64];
  __shared__ bf16 Bl[64 * 64];
  int hbid = blockIdx.x;
  int o = (hbid & 7) * 64 + (hbid >> 3);
  int b = o >> 8;
  int r = o & 255;
  int rx = r >> 5;               // 0..7
  int py = r & 31;
  int r0 = rx * 64;
  int p0 = py * 64;
  int tid = threadIdx.x, w = tid >> 6, lane = tid & 63;
  int wm = w >> 1, wn = w & 1;
  int g = lane >> 4, l15 = lane & 15;

  const bf16* Abase = Wor + (size_t)r0 * 512;

  int srow = tid >> 3;
  int sch = tid & 7;

  f32x4 acc[2][2] = {};

  for (int ks = 0; ks < 8; ++ks) {
    int k0 = ks * 64;
    const bf16* Bbase = oh + (((size_t)b * 8 + ks) * 2048 + p0) * 64;
    __syncthreads();
#pragma unroll
    for (int i = 0; i < 2; ++i) {
      int row = srow + i * 32;
      int ch = sch ^ (row & 7);
      gload_lds16(Abase + (size_t)row * 512 + k0 + ch * 8,
                  Al + (i * 32 + w * 8) * 64);
      gload_lds16(Bbase + (size_t)row * 64 + ch * 8,
                  Bl + (i * 32 + w * 8) * 64);
    }
    __syncthreads();
#pragma unroll
    for (int ks2 = 0; ks2 < 2; ++ks2) {
      bf16x8 a[2], bb[2];
#pragma unroll
      for (int mi = 0; mi < 2; ++mi) {
        int row = wm * 32 + mi * 16 + l15;
        a[mi] = *(const bf16x8*)(Al + row * 64 +
                                 (((ks2 * 4 + g) ^ (row & 7)) << 3));
      }
#pragma unroll
      for (int ni = 0; ni < 2; ++ni) {
        int row = wn * 32 + ni * 16 + l15;
        bb[ni] = *(const bf16x8*)(Bl + row * 64 +
                                  (((ks2 * 4 + g) ^ (row & 7)) << 3));
      }
#pragma unroll
      for (int mi = 0; mi < 2; ++mi)
#pragma unroll
        for (int ni = 0; ni < 2; ++ni)
          acc[mi][ni] = mfma16(a[mi], bb[ni], acc[mi][ni]);
    }
  }

#pragma unroll
  for (int mi = 0; mi < 2; ++mi) {
#pragma unroll
    for (int ni = 0; ni < 2; ++ni) {
#pragma unroll
      for (int r2 = 0; r2 < 4; ++r2) {
        int row = r0 + wm * 32 + mi * 16 + g * 4 + r2;
        int p = p0 + wn * 32 + ni * 16 + l15;
        out[((size_t)b * 512 + row) * 2048 + p] = acc[mi][ni][r2] + bo[row];
      }
    }
  }
}

// ---------------------------------------------------------------------------
extern "C" void kernel_launch(void* const* d_in, const int* in_sizes, int n_in,
                              void* d_out, int out_size, void* d_ws, size_t ws_size,
                              hipStream_t stream) {
  (void)in_sizes; (void)n_in; (void)out_size;
  const float* Q  = (const float*)d_in[0];
  const float* Wq = (const float*)d_in[1];
  const float* bq = (const float*)d_in[2];
  const float* Wk = (const float*)d_in[3];
  const float* bk = (const float*)d_in[4];
  const float* Wv = (const float*)d_in[5];
  const float* bv = (const float*)d_in[6];
  const float* Wo = (const float*)d_in[7];
  const float* bo = (const float*)d_in[8];
  float* out = (float*)d_out;

  char* ws = (char*)d_ws;
  bf16*  Wf    = (bf16*)(ws + 0);          // 1536*512*2  = 1572864
  bf16*  Wor   = (bf16*)(ws + 1572864);    // 512*512*2   = 524288
  float* biasf = (float*)(ws + 2097152);   // 1536*4      = 6144
  bf16*  Qt    = (bf16*)(ws + 2103296);    // 2*2048*512*2 = 4194304
  bf16*  qp    = (bf16*)(ws + 6297600);    // 4194304
  bf16*  kp    = (bf16*)(ws + 10491904);   // 4194304
  bf16*  vt    = (bf16*)(ws + 14686208);   // 4194304 (ends 18880512)

  size_t need4 = 18880512ull + 4ull * 4194304 + 2ull * 4ull * 131072;
  int NS = (ws_size >= need4) ? 4 : 2;
  int TS = 32 / NS;

  bf16*  Opart = (bf16*)(ws + 18880512);               // NS * 4194304 bytes
  float* mbuf  = (float*)(ws + 18880512 + (size_t)NS * 4194304);
  float* lbuf  = (float*)(ws + 18880512 + (size_t)NS * 4194304 +
                          (size_t)NS * 131072);
  bf16*  oh    = Opart;  // combine writes in place over z=0 (race-free)

  prep<<<dim3(768), dim3(256), 0, stream>>>(Q, Wq, bq, Wk, bk, Wv, bv, Wo,
                                            Wf, biasf, Wor, Qt);
  qkv_gemm<<<dim3(768), dim3(256), 0, stream>>>(Wf, Qt, biasf, qp, kp, vt);
  attn_k<<<dim3(16 * NS * 8), dim3(512), 0, stream>>>(qp, kp, vt, Opart, mbuf,
                                                      lbuf, TS);
  combine<<<dim3(512), dim3(256), 0, stream>>>(Opart, mbuf, lbuf, oh, NS);
  out_gemm<<<dim3(512), dim3(256), 0, stream>>>(Wor, oh, bo, out);
}